// Round 1
// baseline (396.867 us; speedup 1.0000x reference)
//
#include <hip/hip_runtime.h>
#include <stdint.h>

typedef __bf16 bf16;
typedef __bf16 bf16x8 __attribute__((ext_vector_type(8)));
typedef __bf16 bf16x4 __attribute__((ext_vector_type(4)));
typedef float floatx4 __attribute__((ext_vector_type(4)));

#define S_LEN 2048
#define DM 1024
#define NH 16
#define DK 64
#define MTOT 4096  // B*S

// ---------------------------------------------------------------------------
// Projection GEMM: Y[m,n] = sum_k X[m,k]*W[n,k] + bias[n]   (NT, k-contiguous)
// z=0: Q -> qb [b,h,s,d] bf16 ; z=1: K -> kb [b,h,s,d] ; z=2: V -> vtb [b,h,d,s]
// Tile 64x64, BK=32, 256 threads (4 waves), wave w owns m-rows [w*16, w*16+16).
// ---------------------------------------------------------------------------
__global__ __launch_bounds__(256) void proj_kernel(
    const float* __restrict__ Xq, const float* __restrict__ Xk, const float* __restrict__ Xv,
    const float* __restrict__ Wqp, const float* __restrict__ Wkp, const float* __restrict__ Wvp,
    const float* __restrict__ bqp, const float* __restrict__ bkp, const float* __restrict__ bvp,
    bf16* __restrict__ qb, bf16* __restrict__ kb, bf16* __restrict__ vtb)
{
  const int z = blockIdx.z;
  const float* X    = (z == 0) ? Xq  : (z == 1) ? Xk  : Xv;
  const float* W    = (z == 0) ? Wqp : (z == 1) ? Wkp : Wvp;
  const float* bias = (z == 0) ? bqp : (z == 1) ? bkp : bvp;

  const int m0 = blockIdx.x * 64;
  const int n0 = blockIdx.y * 64;
  const int tid = threadIdx.x;
  const int lane = tid & 63;
  const int wid = tid >> 6;

  // +8 pad: 40 bf16 = 80B row stride (16B-aligned, 2-way bank alias only)
  __shared__ bf16 As[64][40];
  __shared__ bf16 Bs[64][40];

  floatx4 acc[4] = {{0.f,0.f,0.f,0.f},{0.f,0.f,0.f,0.f},{0.f,0.f,0.f,0.f},{0.f,0.f,0.f,0.f}};

  const int srow = tid >> 3;        // 0..31
  const int scol = (tid & 7) * 4;   // float offset 0..28

  const int mr = lane & 15;         // MFMA a/b row index
  const int k0 = (lane >> 4) * 8;   // MFMA k offset

  for (int kt = 0; kt < DM; kt += 32) {
    __syncthreads();
    #pragma unroll
    for (int p = 0; p < 2; p++) {
      const int r = srow + p * 32;
      float4 xa = *(const float4*)(X + (size_t)(m0 + r) * DM + kt + scol);
      bf16x4 xh; xh[0] = (bf16)xa.x; xh[1] = (bf16)xa.y; xh[2] = (bf16)xa.z; xh[3] = (bf16)xa.w;
      *(bf16x4*)&As[r][scol] = xh;
      float4 wa = *(const float4*)(W + (size_t)(n0 + r) * DM + kt + scol);
      bf16x4 wh; wh[0] = (bf16)wa.x; wh[1] = (bf16)wa.y; wh[2] = (bf16)wa.z; wh[3] = (bf16)wa.w;
      *(bf16x4*)&Bs[r][scol] = wh;
    }
    __syncthreads();

    bf16x8 a = *(const bf16x8*)&As[wid * 16 + mr][k0];
    #pragma unroll
    for (int nt = 0; nt < 4; nt++) {
      bf16x8 b = *(const bf16x8*)&Bs[nt * 16 + mr][k0];
      acc[nt] = __builtin_amdgcn_mfma_f32_16x16x32_bf16(a, b, acc[nt], 0, 0, 0);
    }
  }

  // Epilogue. C/D layout: col = lane&15, row = (lane>>4)*4 + r
  const int mbase = m0 + wid * 16 + (lane >> 4) * 4;
  #pragma unroll
  for (int nt = 0; nt < 4; nt++) {
    const int gn = n0 + nt * 16 + mr;
    const float bv = bias[gn];
    const int h = gn >> 6, d = gn & 63;
    #pragma unroll
    for (int r = 0; r < 4; r++) {
      const int gm = mbase + r;
      const int bi = gm >> 11, s = gm & 2047;
      const bf16 hv = (bf16)(acc[nt][r] + bv);
      if (z == 2) {
        vtb[(((size_t)(bi * NH + h)) * DK + d) * S_LEN + s] = hv;   // V transposed
      } else if (z == 0) {
        qb[(((size_t)(bi * NH + h)) * S_LEN + s) * DK + d] = hv;
      } else {
        kb[(((size_t)(bi * NH + h)) * S_LEN + s) * DK + d] = hv;
      }
    }
  }
}

// ---------------------------------------------------------------------------
// Flash attention: grid (32 q-tiles, 32 b*h), 256 threads (4 waves).
// Q-tile 64 rows; iterate 32 K-tiles of 64 keys. Online softmax in registers.
// ---------------------------------------------------------------------------
__global__ __launch_bounds__(256) void attn_kernel(
    const bf16* __restrict__ qb, const bf16* __restrict__ kb,
    const bf16* __restrict__ vtb, bf16* __restrict__ ob)
{
  const int qt = blockIdx.x;   // 0..31
  const int bh = blockIdx.y;   // 0..31
  const int tid = threadIdx.x;
  const int lane = tid & 63;
  const int wid = tid >> 6;

  const bf16* qh = qb + (size_t)bh * S_LEN * DK;
  const bf16* kh = kb + (size_t)bh * S_LEN * DK;
  const bf16* vh = vtb + (size_t)bh * DK * S_LEN;

  __shared__ bf16 Qs[64][72];
  __shared__ bf16 Ks[64][72];
  __shared__ bf16 Vs[64][72];         // Vs[d][s'] (from transposed V)
  __shared__ bf16 Ps[4][16][72];      // per-wave P tile (C-layout -> A-layout)

  // stage Q tile once
  {
    const int row = tid >> 3;          // 0..31
    const int c = (tid & 7) * 8;       // 0..56
    #pragma unroll
    for (int p = 0; p < 2; p++) {
      const int r = row + p * 32;
      *(int4*)&Qs[r][c] = *(const int4*)(qh + (size_t)(qt * 64 + r) * DK + c);
    }
  }

  floatx4 acc_o[4] = {{0.f,0.f,0.f,0.f},{0.f,0.f,0.f,0.f},{0.f,0.f,0.f,0.f},{0.f,0.f,0.f,0.f}};
  float m_i[4] = {-1e30f, -1e30f, -1e30f, -1e30f};
  float l_i[4] = {0.f, 0.f, 0.f, 0.f};

  const int mr = lane & 15;
  const int q4 = lane >> 4;
  const int k0 = q4 * 8;

  for (int kt2 = 0; kt2 < S_LEN / 64; kt2++) {
    __syncthreads();  // previous iteration done reading Ks/Vs (covers Q stage on iter 0)
    {
      const int row = tid >> 3;
      const int c = (tid & 7) * 8;
      #pragma unroll
      for (int p = 0; p < 2; p++) {
        const int r = row + p * 32;
        *(int4*)&Ks[r][c] = *(const int4*)(kh + (size_t)(kt2 * 64 + r) * DK + c);
        *(int4*)&Vs[r][c] = *(const int4*)(vh + (size_t)r * S_LEN + kt2 * 64 + c);
      }
    }
    __syncthreads();

    // scores: S[m][n] = sum_d Q[m][d] * K[n][d], m = wave's 16 q-rows, n = 64 keys
    floatx4 sc[4] = {{0.f,0.f,0.f,0.f},{0.f,0.f,0.f,0.f},{0.f,0.f,0.f,0.f},{0.f,0.f,0.f,0.f}};
    #pragma unroll
    for (int kk = 0; kk < 2; kk++) {
      bf16x8 a = *(const bf16x8*)&Qs[wid * 16 + mr][kk * 32 + k0];
      #pragma unroll
      for (int nt = 0; nt < 4; nt++) {
        bf16x8 b = *(const bf16x8*)&Ks[nt * 16 + mr][kk * 32 + k0];
        sc[nt] = __builtin_amdgcn_mfma_f32_16x16x32_bf16(a, b, sc[nt], 0, 0, 0);
      }
    }
    #pragma unroll
    for (int nt = 0; nt < 4; nt++) sc[nt] *= 0.125f;  // 1/sqrt(64)

    // online softmax; row m = q4*4 + r lives in 16-lane group, col = nt*16 + mr
    float alpha[4];
    #pragma unroll
    for (int r = 0; r < 4; r++) {
      float mx = fmaxf(fmaxf(sc[0][r], sc[1][r]), fmaxf(sc[2][r], sc[3][r]));
      #pragma unroll
      for (int off = 1; off < 16; off <<= 1) mx = fmaxf(mx, __shfl_xor(mx, off, 16));
      const float mn = fmaxf(m_i[r], mx);
      alpha[r] = __expf(m_i[r] - mn);
      m_i[r] = mn;
      float rs = 0.f;
      #pragma unroll
      for (int nt = 0; nt < 4; nt++) {
        const float pv = __expf(sc[nt][r] - mn);
        sc[nt][r] = pv;
        rs += pv;
      }
      #pragma unroll
      for (int off = 1; off < 16; off <<= 1) rs += __shfl_xor(rs, off, 16);
      l_i[r] = l_i[r] * alpha[r] + rs;
    }

    // P: C-layout regs -> LDS -> A-layout frags (wave-private region)
    #pragma unroll
    for (int nt = 0; nt < 4; nt++)
      #pragma unroll
      for (int r = 0; r < 4; r++)
        Ps[wid][q4 * 4 + r][nt * 16 + mr] = (bf16)sc[nt][r];

    // rescale O accumulator
    #pragma unroll
    for (int dt = 0; dt < 4; dt++)
      #pragma unroll
      for (int r = 0; r < 4; r++)
        acc_o[dt][r] *= alpha[r];

    __syncthreads();  // safety: order Ps writes before reads

    // O[m][d] += sum_s P[m][s] * V[s][d]  (B operand = Vs[d][s], k-contiguous)
    #pragma unroll
    for (int kk = 0; kk < 2; kk++) {
      bf16x8 a = *(const bf16x8*)&Ps[wid][mr][kk * 32 + k0];
      #pragma unroll
      for (int dt = 0; dt < 4; dt++) {
        bf16x8 b = *(const bf16x8*)&Vs[dt * 16 + mr][kk * 32 + k0];
        acc_o[dt] = __builtin_amdgcn_mfma_f32_16x16x32_bf16(a, b, acc_o[dt], 0, 0, 0);
      }
    }
  }

  // epilogue: out[b, s, h*64+d] bf16, concat-heads layout [4096, 1024]
  const int bi = bh >> 4, h = bh & 15;
  #pragma unroll
  for (int dt = 0; dt < 4; dt++) {
    const int d = dt * 16 + mr;
    #pragma unroll
    for (int r = 0; r < 4; r++) {
      const int s = qt * 64 + wid * 16 + q4 * 4 + r;
      const float val = acc_o[dt][r] / l_i[r];
      ob[((size_t)(bi * S_LEN + s)) * DM + h * DK + d] = (bf16)val;
    }
  }
}

// ---------------------------------------------------------------------------
// Output projection: out[m,n] = sum_k AO[m,k]*Wo[n,k] + bo[n], fp32 out
// ---------------------------------------------------------------------------
__global__ __launch_bounds__(256) void oproj_kernel(
    const bf16* __restrict__ X, const float* __restrict__ W,
    const float* __restrict__ bias, float* __restrict__ out)
{
  const int m0 = blockIdx.x * 64;
  const int n0 = blockIdx.y * 64;
  const int tid = threadIdx.x;
  const int lane = tid & 63;
  const int wid = tid >> 6;

  __shared__ bf16 As[64][40];
  __shared__ bf16 Bs[64][40];

  floatx4 acc[4] = {{0.f,0.f,0.f,0.f},{0.f,0.f,0.f,0.f},{0.f,0.f,0.f,0.f},{0.f,0.f,0.f,0.f}};

  const int xrow = tid >> 2;         // 0..63
  const int xcol = (tid & 3) * 8;    // bf16 offset 0..24
  const int wrow = tid >> 3;         // 0..31
  const int wcol = (tid & 7) * 4;    // float offset

  const int mr = lane & 15;
  const int k0 = (lane >> 4) * 8;

  for (int kt = 0; kt < DM; kt += 32) {
    __syncthreads();
    *(int4*)&As[xrow][xcol] = *(const int4*)(X + (size_t)(m0 + xrow) * DM + kt + xcol);
    #pragma unroll
    for (int p = 0; p < 2; p++) {
      const int r = wrow + p * 32;
      float4 wa = *(const float4*)(W + (size_t)(n0 + r) * DM + kt + wcol);
      bf16x4 wh; wh[0] = (bf16)wa.x; wh[1] = (bf16)wa.y; wh[2] = (bf16)wa.z; wh[3] = (bf16)wa.w;
      *(bf16x4*)&Bs[r][wcol] = wh;
    }
    __syncthreads();

    bf16x8 a = *(const bf16x8*)&As[wid * 16 + mr][k0];
    #pragma unroll
    for (int nt = 0; nt < 4; nt++) {
      bf16x8 b = *(const bf16x8*)&Bs[nt * 16 + mr][k0];
      acc[nt] = __builtin_amdgcn_mfma_f32_16x16x32_bf16(a, b, acc[nt], 0, 0, 0);
    }
  }

  const int mbase = m0 + wid * 16 + (lane >> 4) * 4;
  #pragma unroll
  for (int nt = 0; nt < 4; nt++) {
    const int gn = n0 + nt * 16 + mr;
    const float bv = bias[gn];
    #pragma unroll
    for (int r = 0; r < 4; r++) {
      out[(size_t)(mbase + r) * DM + gn] = acc[nt][r] + bv;
    }
  }
}

// ---------------------------------------------------------------------------
extern "C" void kernel_launch(void* const* d_in, const int* in_sizes, int n_in,
                              void* d_out, int out_size, void* d_ws, size_t ws_size,
                              hipStream_t stream) {
  const float* Q  = (const float*)d_in[0];
  const float* K  = (const float*)d_in[1];
  const float* V  = (const float*)d_in[2];
  const float* Wq = (const float*)d_in[3];
  const float* bq = (const float*)d_in[4];
  const float* Wk = (const float*)d_in[5];
  const float* bk = (const float*)d_in[6];
  const float* Wv = (const float*)d_in[7];
  const float* bv = (const float*)d_in[8];
  const float* Wo = (const float*)d_in[9];
  const float* bo = (const float*)d_in[10];
  float* out = (float*)d_out;

  const size_t NE = (size_t)MTOT * DM;      // 4 Mi elems
  bf16* qb  = (bf16*)d_ws;                  // [B,H,S,Dk]
  bf16* kb  = qb + NE;                      // [B,H,S,Dk]
  bf16* vtb = kb + NE;                      // [B,H,Dk,S]
  bf16* ao  = vtb + NE;                     // [B*S, DM] attn output (concat heads)

  proj_kernel<<<dim3(64, 16, 3), 256, 0, stream>>>(Q, K, V, Wq, Wk, Wv, bq, bk, bv, qb, kb, vtb);
  attn_kernel<<<dim3(32, 32), 256, 0, stream>>>(qb, kb, vtb, ao);
  oproj_kernel<<<dim3(64, 16), 256, 0, stream>>>(ao, Wo, bo, out);
}

// Round 2
// 332.441 us; speedup vs baseline: 1.1938x; 1.1938x over previous
//
#include <hip/hip_runtime.h>
#include <stdint.h>

typedef __bf16 bf16;
typedef __bf16 bf16x8 __attribute__((ext_vector_type(8)));
typedef __bf16 bf16x4 __attribute__((ext_vector_type(4)));
typedef float floatx4 __attribute__((ext_vector_type(4)));

#define S_LEN 2048
#define DM 1024
#define NH 16
#define DK 64
#define MTOT 4096  // B*S

// ---------------------------------------------------------------------------
// Projection GEMM: Y[m,n] = sum_k X[m,k]*W[n,k] + bias[n]   (NT, k-contiguous)
// 128x128 tile, BK=32, 256 threads = 4 waves in 2x2; wave does 64x64 (16 MFMA/K-step).
// z=0: Q*0.125 -> qb [b,h,s,d] ; z=1: K -> kb [b,h,s,d] ; z=2: V -> vtb [b,h,d,s]
// ---------------------------------------------------------------------------
__global__ __launch_bounds__(256) void proj_kernel(
    const float* __restrict__ Xq, const float* __restrict__ Xk, const float* __restrict__ Xv,
    const float* __restrict__ Wqp, const float* __restrict__ Wkp, const float* __restrict__ Wvp,
    const float* __restrict__ bqp, const float* __restrict__ bkp, const float* __restrict__ bvp,
    bf16* __restrict__ qb, bf16* __restrict__ kb, bf16* __restrict__ vtb)
{
  const int z = blockIdx.z;
  const float* X    = (z == 0) ? Xq  : (z == 1) ? Xk  : Xv;
  const float* W    = (z == 0) ? Wqp : (z == 1) ? Wkp : Wvp;
  const float* bias = (z == 0) ? bqp : (z == 1) ? bkp : bvp;

  const int m0 = blockIdx.x * 128;
  const int n0 = blockIdx.y * 128;
  const int tid = threadIdx.x;
  const int lane = tid & 63;
  const int wid = tid >> 6;
  const int wm = (wid & 1) * 64;
  const int wn = (wid >> 1) * 64;

  __shared__ bf16 As[128][40];   // stride 80B: rows spread 8 bank-offsets
  __shared__ bf16 Bs[128][40];

  floatx4 acc[4][4];
  #pragma unroll
  for (int i = 0; i < 4; i++)
    #pragma unroll
    for (int j = 0; j < 4; j++) acc[i][j] = (floatx4){0.f, 0.f, 0.f, 0.f};

  const int mr = lane & 15;
  const int q4 = lane >> 4;
  const int k0 = q4 * 8;

  for (int kt = 0; kt < DM; kt += 32) {
    __syncthreads();
    // stage 128x32 fp32 -> bf16. chunk c = tid + 256*j: row=c>>3, col=(c&7)*4
    #pragma unroll
    for (int j = 0; j < 4; j++) {
      const int c = tid + 256 * j;
      const int r = c >> 3, cc = (c & 7) * 4;
      float4 xa = *(const float4*)(X + (size_t)(m0 + r) * DM + kt + cc);
      bf16x4 xh; xh[0] = (bf16)xa.x; xh[1] = (bf16)xa.y; xh[2] = (bf16)xa.z; xh[3] = (bf16)xa.w;
      *(bf16x4*)&As[r][cc] = xh;
      float4 wa = *(const float4*)(W + (size_t)(n0 + r) * DM + kt + cc);
      bf16x4 wh; wh[0] = (bf16)wa.x; wh[1] = (bf16)wa.y; wh[2] = (bf16)wa.z; wh[3] = (bf16)wa.w;
      *(bf16x4*)&Bs[r][cc] = wh;
    }
    __syncthreads();

    bf16x8 af[4], bfr[4];
    #pragma unroll
    for (int mt = 0; mt < 4; mt++) af[mt] = *(const bf16x8*)&As[wm + mt * 16 + mr][k0];
    #pragma unroll
    for (int nt = 0; nt < 4; nt++) bfr[nt] = *(const bf16x8*)&Bs[wn + nt * 16 + mr][k0];
    #pragma unroll
    for (int mt = 0; mt < 4; mt++)
      #pragma unroll
      for (int nt = 0; nt < 4; nt++)
        acc[mt][nt] = __builtin_amdgcn_mfma_f32_16x16x32_bf16(af[mt], bfr[nt], acc[mt][nt], 0, 0, 0);
  }

  // Epilogue. C/D layout: col = lane&15, row = q4*4 + r
  const float qscale = (z == 0) ? 0.125f : 1.0f;   // fold 1/sqrt(Dk) into q
  #pragma unroll
  for (int nt = 0; nt < 4; nt++) {
    const int gn = n0 + wn + nt * 16 + mr;
    const float bv = bias[gn];
    const int h = gn >> 6, d = gn & 63;
    #pragma unroll
    for (int mt = 0; mt < 4; mt++) {
      const int mbase = m0 + wm + mt * 16 + q4 * 4;
      #pragma unroll
      for (int r = 0; r < 4; r++) {
        const int gm = mbase + r;
        const int bi = gm >> 11, s = gm & 2047;
        const bf16 hv = (bf16)((acc[mt][nt][r] + bv) * qscale);
        if (z == 2) {
          vtb[(((size_t)(bi * NH + h)) * DK + d) * S_LEN + s] = hv;   // V transposed
        } else if (z == 0) {
          qb[(((size_t)(bi * NH + h)) * S_LEN + s) * DK + d] = hv;
        } else {
          kb[(((size_t)(bi * NH + h)) * S_LEN + s) * DK + d] = hv;
        }
      }
    }
  }
}

// ---------------------------------------------------------------------------
// Flash attention: grid (32 q-tiles, 32 b*h), 256 threads (4 waves).
// Q-tile 64 rows (wave owns 16); 16 iterations over 128-key tiles.
// Q frags preloaded to registers (q pre-scaled by 1/8 at projection).
// ---------------------------------------------------------------------------
__global__ __launch_bounds__(256) void attn_kernel(
    const bf16* __restrict__ qb, const bf16* __restrict__ kb,
    const bf16* __restrict__ vtb, bf16* __restrict__ ob)
{
  const int qt = blockIdx.x;   // 0..31
  const int bh = blockIdx.y;   // 0..31
  const int tid = threadIdx.x;
  const int lane = tid & 63;
  const int wid = tid >> 6;

  const bf16* qh = qb + (size_t)bh * S_LEN * DK;
  const bf16* kh = kb + (size_t)bh * S_LEN * DK;
  const bf16* vh = vtb + (size_t)bh * DK * S_LEN;

  __shared__ bf16 Ks[128][72];        // [key][d]
  __shared__ bf16 Vs[64][136];        // [d][key]
  __shared__ bf16 Ps[4][16][136];     // per-wave P tile (C-layout -> A-layout)

  const int mr = lane & 15;
  const int q4 = lane >> 4;
  const int k0 = q4 * 8;

  // Q frags: loop-invariant, straight from global
  bf16x8 aq[2];
  #pragma unroll
  for (int kk = 0; kk < 2; kk++)
    aq[kk] = *(const bf16x8*)(qh + (size_t)(qt * 64 + wid * 16 + mr) * DK + kk * 32 + k0);

  floatx4 acc_o[4];
  #pragma unroll
  for (int i = 0; i < 4; i++) acc_o[i] = (floatx4){0.f, 0.f, 0.f, 0.f};
  float m_i[4] = {-1e30f, -1e30f, -1e30f, -1e30f};
  float l_i[4] = {0.f, 0.f, 0.f, 0.f};

  const int krow = tid >> 1;        // 0..127
  const int kcol = (tid & 1) * 32;
  const int vrow = tid >> 2;        // 0..63
  const int vcol = (tid & 3) * 32;

  for (int it = 0; it < S_LEN / 128; it++) {
    const int s0 = it * 128;
    __syncthreads();  // all waves done reading Ks/Vs from previous iteration
    #pragma unroll
    for (int j = 0; j < 4; j++)
      *(int4*)&Ks[krow][kcol + j * 8] = *(const int4*)(kh + (size_t)(s0 + krow) * DK + kcol + j * 8);
    #pragma unroll
    for (int j = 0; j < 4; j++)
      *(int4*)&Vs[vrow][vcol + j * 8] = *(const int4*)(vh + (size_t)vrow * S_LEN + s0 + vcol + j * 8);
    __syncthreads();

    // scores: 16 q-rows x 128 keys per wave (q pre-scaled by 1/8)
    floatx4 sc[8];
    #pragma unroll
    for (int i = 0; i < 8; i++) sc[i] = (floatx4){0.f, 0.f, 0.f, 0.f};
    #pragma unroll
    for (int kk = 0; kk < 2; kk++) {
      #pragma unroll
      for (int nt = 0; nt < 8; nt++) {
        bf16x8 b = *(const bf16x8*)&Ks[nt * 16 + mr][kk * 32 + k0];
        sc[nt] = __builtin_amdgcn_mfma_f32_16x16x32_bf16(aq[kk], b, sc[nt], 0, 0, 0);
      }
    }

    // online softmax; row r lives in a 16-lane group
    float alpha[4];
    #pragma unroll
    for (int r = 0; r < 4; r++) {
      float mx = sc[0][r];
      #pragma unroll
      for (int nt = 1; nt < 8; nt++) mx = fmaxf(mx, sc[nt][r]);
      #pragma unroll
      for (int off = 1; off < 16; off <<= 1) mx = fmaxf(mx, __shfl_xor(mx, off, 16));
      const float mn = fmaxf(m_i[r], mx);
      alpha[r] = __expf(m_i[r] - mn);
      m_i[r] = mn;
      float rs = 0.f;
      #pragma unroll
      for (int nt = 0; nt < 8; nt++) {
        const float pv = __expf(sc[nt][r] - mn);
        sc[nt][r] = pv;
        rs += pv;
      }
      #pragma unroll
      for (int off = 1; off < 16; off <<= 1) rs += __shfl_xor(rs, off, 16);
      l_i[r] = l_i[r] * alpha[r] + rs;
    }

    // P: C-layout regs -> wave-private LDS -> A-layout frags (no barrier needed)
    #pragma unroll
    for (int nt = 0; nt < 8; nt++)
      #pragma unroll
      for (int r = 0; r < 4; r++)
        Ps[wid][q4 * 4 + r][nt * 16 + mr] = (bf16)sc[nt][r];

    #pragma unroll
    for (int dt = 0; dt < 4; dt++)
      #pragma unroll
      for (int r = 0; r < 4; r++)
        acc_o[dt][r] *= alpha[r];

    // O[m][d] += P[m][s] * V[s][d]   (within-wave LDS RAW: compiler inserts lgkmcnt)
    #pragma unroll
    for (int kk2 = 0; kk2 < 4; kk2++) {
      bf16x8 a = *(const bf16x8*)&Ps[wid][mr][kk2 * 32 + k0];
      #pragma unroll
      for (int dt = 0; dt < 4; dt++) {
        bf16x8 b = *(const bf16x8*)&Vs[dt * 16 + mr][kk2 * 32 + k0];
        acc_o[dt] = __builtin_amdgcn_mfma_f32_16x16x32_bf16(a, b, acc_o[dt], 0, 0, 0);
      }
    }
  }

  // epilogue: out[b, s, h*64+d] bf16 (concat-heads [4096, 1024])
  const int bi = bh >> 4, h = bh & 15;
  #pragma unroll
  for (int dt = 0; dt < 4; dt++) {
    const int d = dt * 16 + mr;
    #pragma unroll
    for (int r = 0; r < 4; r++) {
      const int s = qt * 64 + wid * 16 + q4 * 4 + r;
      const float val = acc_o[dt][r] / l_i[r];
      ob[((size_t)(bi * S_LEN + s)) * DM + h * DK + d] = (bf16)val;
    }
  }
}

// ---------------------------------------------------------------------------
// Output projection: out[m,n] = sum_k AO[m,k]*Wo[n,k] + bo[n], fp32 out
// 128x128 tile, BK=32, A bf16, B fp32->bf16
// ---------------------------------------------------------------------------
__global__ __launch_bounds__(256) void oproj_kernel(
    const bf16* __restrict__ X, const float* __restrict__ W,
    const float* __restrict__ bias, float* __restrict__ out)
{
  const int m0 = blockIdx.x * 128;
  const int n0 = blockIdx.y * 128;
  const int tid = threadIdx.x;
  const int lane = tid & 63;
  const int wid = tid >> 6;
  const int wm = (wid & 1) * 64;
  const int wn = (wid >> 1) * 64;

  __shared__ bf16 As[128][40];
  __shared__ bf16 Bs[128][40];

  floatx4 acc[4][4];
  #pragma unroll
  for (int i = 0; i < 4; i++)
    #pragma unroll
    for (int j = 0; j < 4; j++) acc[i][j] = (floatx4){0.f, 0.f, 0.f, 0.f};

  const int mr = lane & 15;
  const int q4 = lane >> 4;
  const int k0 = q4 * 8;

  for (int kt = 0; kt < DM; kt += 32) {
    __syncthreads();
    // A (bf16): chunk c = tid + 256*j: row=c>>2, col=(c&3)*8
    #pragma unroll
    for (int j = 0; j < 2; j++) {
      const int c = tid + 256 * j;
      const int r = c >> 2, cc = (c & 3) * 8;
      *(int4*)&As[r][cc] = *(const int4*)(X + (size_t)(m0 + r) * DM + kt + cc);
    }
    // B (fp32->bf16): chunk c = tid + 256*j: row=c>>3, col=(c&7)*4
    #pragma unroll
    for (int j = 0; j < 4; j++) {
      const int c = tid + 256 * j;
      const int r = c >> 3, cc = (c & 7) * 4;
      float4 wa = *(const float4*)(W + (size_t)(n0 + r) * DM + kt + cc);
      bf16x4 wh; wh[0] = (bf16)wa.x; wh[1] = (bf16)wa.y; wh[2] = (bf16)wa.z; wh[3] = (bf16)wa.w;
      *(bf16x4*)&Bs[r][cc] = wh;
    }
    __syncthreads();

    bf16x8 af[4], bfr[4];
    #pragma unroll
    for (int mt = 0; mt < 4; mt++) af[mt] = *(const bf16x8*)&As[wm + mt * 16 + mr][k0];
    #pragma unroll
    for (int nt = 0; nt < 4; nt++) bfr[nt] = *(const bf16x8*)&Bs[wn + nt * 16 + mr][k0];
    #pragma unroll
    for (int mt = 0; mt < 4; mt++)
      #pragma unroll
      for (int nt = 0; nt < 4; nt++)
        acc[mt][nt] = __builtin_amdgcn_mfma_f32_16x16x32_bf16(af[mt], bfr[nt], acc[mt][nt], 0, 0, 0);
  }

  #pragma unroll
  for (int nt = 0; nt < 4; nt++) {
    const int gn = n0 + wn + nt * 16 + mr;
    const float bv = bias[gn];
    #pragma unroll
    for (int mt = 0; mt < 4; mt++) {
      const int mbase = m0 + wm + mt * 16 + q4 * 4;
      #pragma unroll
      for (int r = 0; r < 4; r++)
        out[(size_t)(mbase + r) * DM + gn] = acc[mt][nt][r] + bv;
    }
  }
}

// ---------------------------------------------------------------------------
extern "C" void kernel_launch(void* const* d_in, const int* in_sizes, int n_in,
                              void* d_out, int out_size, void* d_ws, size_t ws_size,
                              hipStream_t stream) {
  const float* Q  = (const float*)d_in[0];
  const float* K  = (const float*)d_in[1];
  const float* V  = (const float*)d_in[2];
  const float* Wq = (const float*)d_in[3];
  const float* bq = (const float*)d_in[4];
  const float* Wk = (const float*)d_in[5];
  const float* bk = (const float*)d_in[6];
  const float* Wv = (const float*)d_in[7];
  const float* bv = (const float*)d_in[8];
  const float* Wo = (const float*)d_in[9];
  const float* bo = (const float*)d_in[10];
  float* out = (float*)d_out;

  const size_t NE = (size_t)MTOT * DM;      // 4 Mi elems
  bf16* qb  = (bf16*)d_ws;                  // [B,H,S,Dk] (pre-scaled by 1/8)
  bf16* kb  = qb + NE;                      // [B,H,S,Dk]
  bf16* vtb = kb + NE;                      // [B,H,Dk,S]
  bf16* ao  = vtb + NE;                     // [B*S, DM] attn output (concat heads)

  proj_kernel<<<dim3(32, 8, 3), 256, 0, stream>>>(Q, K, V, Wq, Wk, Wv, bq, bk, bv, qb, kb, vtb);
  attn_kernel<<<dim3(32, 32), 256, 0, stream>>>(qb, kb, vtb, ao);
  oproj_kernel<<<dim3(32, 8), 256, 0, stream>>>(ao, Wo, bo, out);
}